// Round 2
// baseline (482.411 us; speedup 1.0000x reference)
//
#include <hip/hip_runtime.h>
#include <stdint.h>

// SpatialGraphConv fused: 1x1 conv (192x64 GEMM) -> graph matmul (K=75) -> BN.
// B=64, C_in=64, T=300, V=25, K=3, C_out=64.  MFMA bf16 16x16x32, fp32 acc.
//
// v3: main writes a DENSE fp16 tile per block into workspace (no scattered
// fp32 out writes, no partial-line RMW); norm pass reads dense fp16 tiles and
// writes out in linear fp32 order.  15 t per block (5 sub-iters of TT=3).
// Falls back to the v2 path (scattered fp32 out + in-place norm) if the
// workspace is too small.

#define TT 3             // t per sub-iteration
#define NSUB 5           // sub-iterations per block
#define CHT (TT * NSUB)  // 15 t per block
#define NPIX (TT * 25)   // 75 pixels per sub-tile
#define NT1 5            // ceil(80/16) n-tiles for stage 1 (cols 75..79 pad)
#define NBLK 1280        // 64 b * 20 t-chunks
#define TROW 376         // padded fp16 row stride in tile (375 valid + 1 pad)
#define TSZ  24064       // 64 * 376 shorts per tile

typedef short bf16x8 __attribute__((ext_vector_type(8)));
typedef float f32x4 __attribute__((ext_vector_type(4)));

union frag_u { bf16x8 v; uint32_t u[4]; };

__device__ inline short f2bf(float f) {
    union { float f; uint32_t u; } v; v.f = f;
    uint32_t u = v.u;
    u += 0x7fffu + ((u >> 16) & 1u);   // RNE
    return (short)(u >> 16);
}

__device__ inline uint32_t cvtpk(float lo, float hi) {
    uint32_t d;
    asm("v_cvt_pk_bf16_f32 %0, %1, %2" : "=v"(d) : "v"(lo), "v"(hi));
    return d;
}

__device__ inline short f2h(float f) {
    union { _Float16 h; short s; } u; u.h = (_Float16)f; return u.s;
}
__device__ inline float h2f(short s) {
    union { short s; _Float16 h; } u; u.s = s; return (float)u.h;
}

// ---------------------------------------------------------------------------
// main: per block (b, 15-t chunk): 5x { stage1 GEMM -> Ylds -> stage2 } ->
// dense fp16 tile in ws + stats atomics.
// ---------------------------------------------------------------------------
__global__ __launch_bounds__(256, 3) void sgc_main(
    const float* __restrict__ x, const float* __restrict__ W,
    const float* __restrict__ bias, const float* __restrict__ A,
    short* __restrict__ ws, float* __restrict__ stats_part)
{
    __shared__ __align__(16) short Ylds[18432];  // 3 t * 4 cq * 3 k * 64 * 8
    __shared__ __align__(16) short Acat[3072];   // (kb2*2+nt2) * 64 * 8

    const int tid  = threadIdx.x;
    const int lane = tid & 63;
    const int wave = tid >> 6;
    const int q4   = lane >> 4;
    const int wl   = lane & 15;
    const int bid  = blockIdx.x;
    const int b    = bid / 20;
    const int t0   = (bid % 20) * CHT;

    // ---- zero only the kv-pad slabs of Ylds (oct 3 of each of 36 tiles) ----
    {
        bf16x8 z8 = {0,0,0,0,0,0,0,0};
        #pragma unroll
        for (int j = 0; j < 3; ++j) {
            int s = tid + 256 * j;
            if (s < 576)
                *(bf16x8*)&Ylds[(s >> 4) * 512 + 384 + (s & 15) * 8] = z8;
        }
    }

    // ---- Acat fragment table: granule g = (kb2*2+nt2)*64 + oct*16 + w15 ----
    #pragma unroll
    for (int j = 0; j < 2; ++j) {
        int g = tid + 256 * j;
        if (g < 384) {
            int tile = g >> 6;
            int kb2  = tile >> 1, nt2 = tile & 1;
            int oct  = (g >> 4) & 3;
            int w    = nt2 * 16 + (g & 15);
            frag_u fr;
            #pragma unroll
            for (int p = 0; p < 4; ++p) {
                int v0 = oct * 8 + 2 * p;
                float a0 = (w < 25 && v0     < 25) ? A[(kb2 * 25 + v0) * 25 + w]     : 0.f;
                float a1 = (w < 25 && v0 + 1 < 25) ? A[(kb2 * 25 + v0 + 1) * 25 + w] : 0.f;
                fr.u[p] = cvtpk(a0, a1);
            }
            *(bf16x8*)&Acat[g * 8] = fr.v;
        }
    }

    // ---- W A-frags straight from global (L2-resident, 49 KB total) ----
    bf16x8 wfrag[3][2];
    #pragma unroll
    for (int mti = 0; mti < 3; ++mti) {
        int o = (wave * 3 + mti) * 16 + wl;
        #pragma unroll
        for (int kb = 0; kb < 2; ++kb) {
            int ci0 = kb * 32 + q4 * 8;
            const float4 f0 = *(const float4*)&W[o * 64 + ci0];
            const float4 f1 = *(const float4*)&W[o * 64 + ci0 + 4];
            frag_u fr;
            fr.u[0] = cvtpk(f0.x, f0.y);
            fr.u[1] = cvtpk(f0.z, f0.w);
            fr.u[2] = cvtpk(f1.x, f1.y);
            fr.u[3] = cvtpk(f1.z, f1.w);
            wfrag[mti][kb] = fr.v;
        }
    }

    // bias per (mti, r):  o = (wave*3+mti)*16 + q4*4 + r
    float4 bv[3];
    #pragma unroll
    for (int mti = 0; mti < 3; ++mti)
        bv[mti] = *(const float4*)&bias[(wave * 3 + mti) * 16 + q4 * 4];

    __syncthreads();

    // ---- stage-2 B fragments (once per block) ----
    bf16x8 bfrag2[2][3];
    #pragma unroll
    for (int nt2 = 0; nt2 < 2; ++nt2)
        #pragma unroll
        for (int kb2 = 0; kb2 < 3; ++kb2)
            bfrag2[nt2][kb2] = *(const bf16x8*)&Acat[((kb2 * 2 + nt2) * 64 + lane) * 8];

    float ssum[4] = {0.f, 0.f, 0.f, 0.f};
    float ssq[4]  = {0.f, 0.f, 0.f, 0.f};
    const int c0 = wave * 16 + q4 * 4;
    short* wstile = ws + (size_t)bid * TSZ;

    for (int s = 0; s < NSUB; ++s) {
        // ---- stage 1: Y(192 x 75) = W(192x64) @ x(64x75), frags from global.
        const float* xp = x + (size_t)b * 480000 + (size_t)(t0 + s * TT) * 25;
        f32x4 acc[3][NT1];
        #pragma unroll
        for (int mti = 0; mti < 3; ++mti)
            #pragma unroll
            for (int nt = 0; nt < NT1; ++nt) {
                f32x4 zf = {0.f, 0.f, 0.f, 0.f};
                acc[mti][nt] = zf;
            }

        #pragma unroll
        for (int nt = 0; nt < NT1; ++nt) {
            int n = nt * 16 + wl;
            if (n > NPIX - 1) n = NPIX - 1;   // clamp pad cols (discarded later)
            int loff = q4 * 60000 + n;
            bf16x8 xb[2];
            #pragma unroll
            for (int kb = 0; kb < 2; ++kb) {
                float xv[8];
                #pragma unroll
                for (int jj = 0; jj < 8; ++jj)
                    xv[jj] = (xp + (kb * 32 + jj) * 7500)[loff];
                frag_u fr;
                #pragma unroll
                for (int p = 0; p < 4; ++p)
                    fr.u[p] = cvtpk(xv[2 * p], xv[2 * p + 1]);
                xb[kb] = fr.v;
            }
            #pragma unroll
            for (int mti = 0; mti < 3; ++mti) {
                acc[mti][nt] = __builtin_amdgcn_mfma_f32_16x16x32_bf16(
                    wfrag[mti][0], xb[0], acc[mti][nt], 0, 0, 0);
                acc[mti][nt] = __builtin_amdgcn_mfma_f32_16x16x32_bf16(
                    wfrag[mti][1], xb[1], acc[mti][nt], 0, 0, 0);
            }
        }

        __syncthreads();   // prev stage-2 reads done before overwriting Ylds

        // ---- epilogue: Y + bias -> Ylds (fragment-linear for stage-2 A) ----
        #pragma unroll
        for (int nt = 0; nt < NT1; ++nt) {
            int n = nt * 16 + wl;
            if (n < NPIX) {
                int t = n / 25, v = n % 25;
                #pragma unroll
                for (int mti = 0; mti < 3; ++mti) {
                    int wt = wave * 3 + mti;
                    int k  = wt >> 2, cq = wt & 3;
                    int kv = k * 32 + v;
                    int sbase = ((t * 4 + cq) * 3 + k) * 512
                              + ((kv >> 3) & 3) * 128 + q4 * 32 + (kv & 7);
                    const float* bp = (const float*)&bv[mti];
                    #pragma unroll
                    for (int r = 0; r < 4; ++r)
                        Ylds[sbase + r * 8] = f2bf(acc[mti][nt][r] + bp[r]);
                }
            }
        }
        __syncthreads();

        // ---- stage 2: out_t(64x25) = Yt(64x96) @ Acat(96x25), per t ----
        #pragma unroll
        for (int t = 0; t < TT; ++t) {
            bf16x8 a2[3];
            #pragma unroll
            for (int kb2 = 0; kb2 < 3; ++kb2)
                a2[kb2] = *(const bf16x8*)&Ylds[(((t * 4 + wave) * 3 + kb2) * 64 + lane) * 8];

            f32x4 acc2[2];
            #pragma unroll
            for (int nt2 = 0; nt2 < 2; ++nt2) {
                f32x4 zf = {0.f, 0.f, 0.f, 0.f};
                acc2[nt2] = zf;
                #pragma unroll
                for (int kb2 = 0; kb2 < 3; ++kb2)
                    acc2[nt2] = __builtin_amdgcn_mfma_f32_16x16x32_bf16(
                        a2[kb2], bfrag2[nt2][kb2], acc2[nt2], 0, 0, 0);
            }

            int tloc = s * TT + t;
            #pragma unroll
            for (int nt2 = 0; nt2 < 2; ++nt2) {
                int w = nt2 * 16 + wl;
                bool valid = (w < 25);
                #pragma unroll
                for (int r = 0; r < 4; ++r) {
                    float val = acc2[nt2][r];
                    if (valid) {
                        wstile[(c0 + r) * TROW + tloc * 25 + w] = f2h(val);
                        ssum[r] += val;
                        ssq[r]  += val * val;
                    }
                }
            }
        }
    }

    // ---- per-channel partial stats: reduce over the 16 w-lanes ----
    #pragma unroll
    for (int r = 0; r < 4; ++r) {
        float s = ssum[r], q = ssq[r];
        #pragma unroll
        for (int d = 1; d < 16; d <<= 1) {
            s += __shfl_xor(s, d);
            q += __shfl_xor(q, d);
        }
        if (wl == 0) {
            int c = c0 + r;
            int slot = bid & 63;
            atomicAdd(&stats_part[slot * 128 + c], s);
            atomicAdd(&stats_part[slot * 128 + 64 + c], q);
        }
    }
}

__global__ void sgc_finalize(const float* __restrict__ stats_part,
                             const float* __restrict__ gamma,
                             const float* __restrict__ beta,
                             float* __restrict__ scaleshift)
{
    int c = threadIdx.x;  // 64 threads
    float s = 0.f, q = 0.f;
    #pragma unroll 8
    for (int slot = 0; slot < 64; ++slot) {
        s += stats_part[slot * 128 + c];
        q += stats_part[slot * 128 + 64 + c];
    }
    const float invN = 1.f / 480000.f;
    float mean = s * invN;
    float var  = q * invN - mean * mean;
    float rstd = rsqrtf(var + 1e-5f);
    float sc = rstd * gamma[c];
    scaleshift[c]      = sc;
    scaleshift[64 + c] = beta[c] - mean * sc;
}

// ---- norm: dense fp16 tile -> linear fp32 out, stats applied ----
__global__ __launch_bounds__(256) void sgc_normws(
    const short* __restrict__ ws, const float* __restrict__ scaleshift,
    float* __restrict__ out)
{
    const int tid = threadIdx.x;
    const int bid = blockIdx.x;
    const int b   = bid / 20;
    const int chunk = bid % 20;
    const short* tile = ws + (size_t)bid * TSZ;
    float* obase = out + (size_t)b * 480000 + (size_t)chunk * (CHT * 25);

    int i = tid;
    #pragma unroll 3
    for (int j = 0; j < 93; ++j, i += 256) {
        int c = i / 375;
        int rem = i - c * 375;
        float y = h2f(tile[c * TROW + rem]);
        obase[c * 7500 + rem] = y * scaleshift[c] + scaleshift[64 + c];
    }
    if (i < 24000) {
        int c = i / 375;
        int rem = i - c * 375;
        float y = h2f(tile[c * TROW + rem]);
        obase[c * 7500 + rem] = y * scaleshift[c] + scaleshift[64 + c];
    }
}

// ===========================================================================
// Fallback path (workspace too small): v2 kernels — scattered fp32 out +
// in-place norm.
// ===========================================================================
__global__ __launch_bounds__(256, 3) void sgc_main_fb(
    const float* __restrict__ x, const float* __restrict__ W,
    const float* __restrict__ bias, const float* __restrict__ A,
    float* __restrict__ out, float* __restrict__ stats_part)
{
    __shared__ __align__(16) short Ylds[18432];
    __shared__ __align__(16) short Acat[3072];

    const int tid  = threadIdx.x;
    const int lane = tid & 63;
    const int wave = tid >> 6;
    const int q4   = lane >> 4;
    const int wl   = lane & 15;
    const int bid  = blockIdx.x;
    const int b    = bid / 100;
    const int t0   = (bid % 100) * TT;

    {
        bf16x8 z8 = {0,0,0,0,0,0,0,0};
        #pragma unroll
        for (int j = 0; j < 3; ++j) {
            int s = tid + 256 * j;
            if (s < 576)
                *(bf16x8*)&Ylds[(s >> 4) * 512 + 384 + (s & 15) * 8] = z8;
        }
    }

    #pragma unroll
    for (int j = 0; j < 2; ++j) {
        int g = tid + 256 * j;
        if (g < 384) {
            int tile = g >> 6;
            int kb2  = tile >> 1, nt2 = tile & 1;
            int oct  = (g >> 4) & 3;
            int w    = nt2 * 16 + (g & 15);
            frag_u fr;
            #pragma unroll
            for (int p = 0; p < 4; ++p) {
                int v0 = oct * 8 + 2 * p;
                float a0 = (w < 25 && v0     < 25) ? A[(kb2 * 25 + v0) * 25 + w]     : 0.f;
                float a1 = (w < 25 && v0 + 1 < 25) ? A[(kb2 * 25 + v0 + 1) * 25 + w] : 0.f;
                fr.u[p] = cvtpk(a0, a1);
            }
            *(bf16x8*)&Acat[g * 8] = fr.v;
        }
    }

    bf16x8 wfrag[3][2];
    #pragma unroll
    for (int mti = 0; mti < 3; ++mti) {
        int o = (wave * 3 + mti) * 16 + wl;
        #pragma unroll
        for (int kb = 0; kb < 2; ++kb) {
            int ci0 = kb * 32 + q4 * 8;
            const float4 f0 = *(const float4*)&W[o * 64 + ci0];
            const float4 f1 = *(const float4*)&W[o * 64 + ci0 + 4];
            frag_u fr;
            fr.u[0] = cvtpk(f0.x, f0.y);
            fr.u[1] = cvtpk(f0.z, f0.w);
            fr.u[2] = cvtpk(f1.x, f1.y);
            fr.u[3] = cvtpk(f1.z, f1.w);
            wfrag[mti][kb] = fr.v;
        }
    }

    const float* xp = x + (size_t)b * 480000 + (size_t)t0 * 25;
    f32x4 acc[3][NT1];
    #pragma unroll
    for (int mti = 0; mti < 3; ++mti)
        #pragma unroll
        for (int nt = 0; nt < NT1; ++nt) {
            f32x4 zf = {0.f, 0.f, 0.f, 0.f};
            acc[mti][nt] = zf;
        }

    #pragma unroll
    for (int nt = 0; nt < NT1; ++nt) {
        int n = nt * 16 + wl;
        if (n > NPIX - 1) n = NPIX - 1;
        int loff = q4 * 60000 + n;
        bf16x8 xb[2];
        #pragma unroll
        for (int kb = 0; kb < 2; ++kb) {
            float xv[8];
            #pragma unroll
            for (int jj = 0; jj < 8; ++jj)
                xv[jj] = (xp + (kb * 32 + jj) * 7500)[loff];
            frag_u fr;
            #pragma unroll
            for (int p = 0; p < 4; ++p)
                fr.u[p] = cvtpk(xv[2 * p], xv[2 * p + 1]);
            xb[kb] = fr.v;
        }
        #pragma unroll
        for (int mti = 0; mti < 3; ++mti) {
            acc[mti][nt] = __builtin_amdgcn_mfma_f32_16x16x32_bf16(
                wfrag[mti][0], xb[0], acc[mti][nt], 0, 0, 0);
            acc[mti][nt] = __builtin_amdgcn_mfma_f32_16x16x32_bf16(
                wfrag[mti][1], xb[1], acc[mti][nt], 0, 0, 0);
        }
    }

    float4 bv[3];
    #pragma unroll
    for (int mti = 0; mti < 3; ++mti)
        bv[mti] = *(const float4*)&bias[(wave * 3 + mti) * 16 + q4 * 4];

    __syncthreads();

    #pragma unroll
    for (int nt = 0; nt < NT1; ++nt) {
        int n = nt * 16 + wl;
        if (n < NPIX) {
            int t = n / 25, v = n % 25;
            #pragma unroll
            for (int mti = 0; mti < 3; ++mti) {
                int wt = wave * 3 + mti;
                int k  = wt >> 2, cq = wt & 3;
                int kv = k * 32 + v;
                int sbase = ((t * 4 + cq) * 3 + k) * 512
                          + ((kv >> 3) & 3) * 128 + q4 * 32 + (kv & 7);
                const float* bp = (const float*)&bv[mti];
                #pragma unroll
                for (int r = 0; r < 4; ++r)
                    Ylds[sbase + r * 8] = f2bf(acc[mti][nt][r] + bp[r]);
            }
        }
    }
    __syncthreads();

    bf16x8 bfrag2[2][3];
    #pragma unroll
    for (int nt2 = 0; nt2 < 2; ++nt2)
        #pragma unroll
        for (int kb2 = 0; kb2 < 3; ++kb2)
            bfrag2[nt2][kb2] = *(const bf16x8*)&Acat[((kb2 * 2 + nt2) * 64 + lane) * 8];

    float ssum[4] = {0.f, 0.f, 0.f, 0.f};
    float ssq[4]  = {0.f, 0.f, 0.f, 0.f};
    const int c0 = wave * 16 + q4 * 4;

    #pragma unroll
    for (int t = 0; t < TT; ++t) {
        bf16x8 a2[3];
        #pragma unroll
        for (int kb2 = 0; kb2 < 3; ++kb2)
            a2[kb2] = *(const bf16x8*)&Ylds[(((t * 4 + wave) * 3 + kb2) * 64 + lane) * 8];

        f32x4 acc2[2];
        #pragma unroll
        for (int nt2 = 0; nt2 < 2; ++nt2) {
            f32x4 zf = {0.f, 0.f, 0.f, 0.f};
            acc2[nt2] = zf;
            #pragma unroll
            for (int kb2 = 0; kb2 < 3; ++kb2)
                acc2[nt2] = __builtin_amdgcn_mfma_f32_16x16x32_bf16(
                    a2[kb2], bfrag2[nt2][kb2], acc2[nt2], 0, 0, 0);
        }

        #pragma unroll
        for (int nt2 = 0; nt2 < 2; ++nt2) {
            int w = nt2 * 16 + wl;
            bool valid = (w < 25);
            #pragma unroll
            for (int r = 0; r < 4; ++r) {
                float val = acc2[nt2][r];
                if (valid) {
                    out[(size_t)((b * 64 + c0 + r) * 300 + t0 + t) * 25 + w] = val;
                    ssum[r] += val;
                    ssq[r]  += val * val;
                }
            }
        }
    }

    #pragma unroll
    for (int r = 0; r < 4; ++r) {
        float s = ssum[r], q = ssq[r];
        #pragma unroll
        for (int d = 1; d < 16; d <<= 1) {
            s += __shfl_xor(s, d);
            q += __shfl_xor(q, d);
        }
        if (wl == 0) {
            int c = c0 + r;
            int slot = bid & 63;
            atomicAdd(&stats_part[slot * 128 + c], s);
            atomicAdd(&stats_part[slot * 128 + 64 + c], q);
        }
    }
}

__global__ __launch_bounds__(256) void sgc_norm_fb(float* __restrict__ out,
                                                   const float* __restrict__ scaleshift)
{
    const int total4 = 30720000 / 4;
    int stride = gridDim.x * 256;
    for (int i = blockIdx.x * 256 + threadIdx.x; i < total4; i += stride) {
        int c = (i / 1875) & 63;
        float sc = scaleshift[c], sh = scaleshift[64 + c];
        float4 v = *((float4*)out + i);
        v.x = v.x * sc + sh;
        v.y = v.y * sc + sh;
        v.z = v.z * sc + sh;
        v.w = v.w * sc + sh;
        *((float4*)out + i) = v;
    }
}

extern "C" void kernel_launch(void* const* d_in, const int* in_sizes, int n_in,
                              void* d_out, int out_size, void* d_ws, size_t ws_size,
                              hipStream_t stream)
{
    const float* x     = (const float*)d_in[0];
    const float* W     = (const float*)d_in[1];
    const float* bias  = (const float*)d_in[2];
    const float* A     = (const float*)d_in[3];
    const float* gamma = (const float*)d_in[4];
    const float* beta  = (const float*)d_in[5];
    float* out = (float*)d_out;

    const size_t tile_bytes = (size_t)NBLK * TSZ * sizeof(short);   // 61.6 MB
    const size_t need = tile_bytes + 64 * 128 * sizeof(float) + 128 * sizeof(float);

    if (ws_size >= need) {
        short* tiles      = (short*)d_ws;
        float* stats      = (float*)((char*)d_ws + tile_bytes);
        float* scaleshift = stats + 64 * 128;

        hipMemsetAsync(stats, 0, 64 * 128 * sizeof(float), stream);
        sgc_main<<<NBLK, 256, 0, stream>>>(x, W, bias, A, tiles, stats);
        sgc_finalize<<<1, 64, 0, stream>>>(stats, gamma, beta, scaleshift);
        sgc_normws<<<NBLK, 256, 0, stream>>>(tiles, scaleshift, out);
    } else {
        float* stats      = (float*)d_ws;
        float* scaleshift = stats + 64 * 128;

        hipMemsetAsync(stats, 0, 64 * 128 * sizeof(float), stream);
        sgc_main_fb<<<6400, 256, 0, stream>>>(x, W, bias, A, out, stats);
        sgc_finalize<<<1, 64, 0, stream>>>(stats, gamma, beta, scaleshift);
        sgc_norm_fb<<<4096, 256, 0, stream>>>(out, scaleshift);
    }
}

// Round 3
// 344.167 us; speedup vs baseline: 1.4017x; 1.4017x over previous
//
#include <hip/hip_runtime.h>
#include <stdint.h>

// SpatialGraphConv fused: 1x1 conv (192x64 GEMM) -> graph matmul (K=75) -> BN.
// B=64, C_in=64, T=300, V=25, K=3, C_out=64.  MFMA bf16 16x16x32, fp32 acc.
//
// v4: latency-oriented rebuild of main.
//  - x tile staged to LDS with 16 independent float4 loads per wave (one
//    latency exposure), transposed [px][ci] stride-68 so stage-1 fragments
//    are 2x ds_read_b128 + cvt_pk (no scalar global loads).
//  - per-wave k-major mapping: each wave owns 16 channels end-to-end; Ylds
//    is wave-private (no cross-wave stage-2 dependency, 2 barriers total).
//  - xT and Ylds alias one 36.9 KB region (disjoint live ranges) -> 4
//    blocks/CU, 50% occupancy.
//  - A fragments straight from global (L1-resident); dense fp16 tile output
//    (9.6 KB/block) + tile-linear norm pass.

#define TT 3            // t per block
#define NPIX (TT * 25)  // 75 pixels
#define NT1 5           // n-tiles (cols 75..79 pad)
#define NBLK 6400       // 64 b * 100 t-chunks
#define XSTRIDE 68      // xT row stride in floats (272 B, 16B-aligned)
#define TSZ 4800        // shorts per output tile (64c * 75px)

typedef short bf16x8 __attribute__((ext_vector_type(8)));
typedef float f32x4 __attribute__((ext_vector_type(4)));

union frag_u { bf16x8 v; uint32_t u[4]; };

__device__ inline short f2bf(float f) {
    union { float f; uint32_t u; } v; v.f = f;
    uint32_t u = v.u;
    u += 0x7fffu + ((u >> 16) & 1u);   // RNE
    return (short)(u >> 16);
}

__device__ inline uint32_t cvtpk(float lo, float hi) {
    uint32_t d;
    asm("v_cvt_pk_bf16_f32 %0, %1, %2" : "=v"(d) : "v"(lo), "v"(hi));
    return d;
}

__device__ inline short f2h(float f) {
    union { _Float16 h; short s; } u; u.h = (_Float16)f; return u.s;
}
__device__ inline float h2f(short s) {
    union { short s; _Float16 h; } u; u.s = s; return (float)u.h;
}

__global__ __launch_bounds__(256, 4) void sgc_main(
    const float* __restrict__ x, const float* __restrict__ W,
    const float* __restrict__ bias, const float* __restrict__ A,
    short* __restrict__ ws, float* __restrict__ stats_part)
{
    // one 36864-B region, two disjoint-lifetime views
    __shared__ __align__(16) short smem[18432];
    float* xT   = (float*)smem;   // [75][68] floats (20400 B used)
    short* Ylds = smem;           // 4 waves * 9 tiles * 512 shorts

    const int tid  = threadIdx.x;
    const int lane = tid & 63;
    const int wave = tid >> 6;
    const int q4   = lane >> 4;
    const int wl   = lane & 15;
    const int bid  = blockIdx.x;
    const int b    = bid / 100;
    const int t0   = (bid % 100) * TT;

    // ---- W A-frags from global (L2/L1-resident), issued with x staging ----
    // wave owns channels c = wave*16..+15 for ALL k: o = k*64 + wave*16 + wl
    bf16x8 wfrag[3][2];
    #pragma unroll
    for (int k = 0; k < 3; ++k) {
        int o = k * 64 + wave * 16 + wl;
        #pragma unroll
        for (int kb = 0; kb < 2; ++kb) {
            int ci0 = kb * 32 + q4 * 8;
            const float4 f0 = *(const float4*)&W[o * 64 + ci0];
            const float4 f1 = *(const float4*)&W[o * 64 + ci0 + 4];
            frag_u fr;
            fr.u[0] = cvtpk(f0.x, f0.y);
            fr.u[1] = cvtpk(f0.z, f0.w);
            fr.u[2] = cvtpk(f1.x, f1.y);
            fr.u[3] = cvtpk(f1.z, f1.w);
            wfrag[k][kb] = fr.v;
        }
    }

    // ---- stage x -> xT[px][ci] (fp32, transposed).  All loads independent,
    // issued before any LDS write: one latency exposure per block. ----
    // thread q = tid + 256j: ci = lane (per-wave), seg = wave + 4j (uniform).
    {
        const float* xg = x + (size_t)b * 480000 + (size_t)t0 * 25 + lane * 7500;
        float4 vv[5];
        int segs[5];
        #pragma unroll
        for (int j = 0; j < 5; ++j) {
            int seg = wave + 4 * j;          // 0..19, valid < 19
            segs[j] = seg;
            if (seg < 18) {
                vv[j] = *(const float4*)(xg + seg * 4);
            } else if (seg == 18) {          // px 72,73,74 only (avoid OOB)
                vv[j].x = xg[72]; vv[j].y = xg[73]; vv[j].z = xg[74]; vv[j].w = 0.f;
            }
        }
        #pragma unroll
        for (int j = 0; j < 5; ++j) {
            int seg = segs[j];
            if (seg < 19) {
                int px0 = seg * 4;
                xT[(px0 + 0) * XSTRIDE + lane] = vv[j].x;
                xT[(px0 + 1) * XSTRIDE + lane] = vv[j].y;
                xT[(px0 + 2) * XSTRIDE + lane] = vv[j].z;
                if (seg < 18) xT[(px0 + 3) * XSTRIDE + lane] = vv[j].w;
            }
        }
    }

    __syncthreads();   // xT ready

    // ---- stage 1: Y(192x75) = W @ x.  Frags via ds_read_b128 + cvt_pk. ----
    f32x4 acc[3][NT1];
    #pragma unroll
    for (int k = 0; k < 3; ++k)
        #pragma unroll
        for (int nt = 0; nt < NT1; ++nt) {
            f32x4 zf = {0.f, 0.f, 0.f, 0.f};
            acc[k][nt] = zf;
        }

    #pragma unroll
    for (int nt = 0; nt < NT1; ++nt) {
        int px = nt * 16 + wl;
        if (px > 74) px = 74;                 // pad cols duplicate px74
        const float* row = &xT[px * XSTRIDE + q4 * 8];
        float4 q0 = *(const float4*)&row[0];
        float4 q1 = *(const float4*)&row[4];
        float4 q2 = *(const float4*)&row[32];
        float4 q3 = *(const float4*)&row[36];
        frag_u x0, x1;
        x0.u[0] = cvtpk(q0.x, q0.y); x0.u[1] = cvtpk(q0.z, q0.w);
        x0.u[2] = cvtpk(q1.x, q1.y); x0.u[3] = cvtpk(q1.z, q1.w);
        x1.u[0] = cvtpk(q2.x, q2.y); x1.u[1] = cvtpk(q2.z, q2.w);
        x1.u[2] = cvtpk(q3.x, q3.y); x1.u[3] = cvtpk(q3.z, q3.w);
        #pragma unroll
        for (int k = 0; k < 3; ++k) {
            acc[k][nt] = __builtin_amdgcn_mfma_f32_16x16x32_bf16(
                wfrag[k][0], x0.v, acc[k][nt], 0, 0, 0);
            acc[k][nt] = __builtin_amdgcn_mfma_f32_16x16x32_bf16(
                wfrag[k][1], x1.v, acc[k][nt], 0, 0, 0);
        }
    }

    __syncthreads();   // all waves done reading xT; region becomes Ylds

    const int wbase = wave * 4608;   // shorts

    // ---- zero kv-pad slabs (oct 3) of this wave's 9 tiles ----
    #pragma unroll
    for (int tile = 0; tile < 9; ++tile)
        *(int*)&Ylds[wbase + tile * 512 + 384 + lane * 2] = 0;

    // ---- bias (L1-hot) ----
    float4 bv[3];
    #pragma unroll
    for (int k = 0; k < 3; ++k)
        bv[k] = *(const float4*)&bias[k * 64 + wave * 16 + q4 * 4];

    // ---- epilogue: Y + bias -> wave-private Ylds (A-frag layout) ----
    #pragma unroll
    for (int nt = 0; nt < NT1; ++nt) {
        int n = nt * 16 + wl;
        if (n < NPIX) {
            int t = n / 25, v = n - t * 25;
            #pragma unroll
            for (int k = 0; k < 3; ++k) {
                int base = wbase + (t * 3 + k) * 512
                         + (v >> 3) * 128 + q4 * 32 + (v & 7);
                const float* bp = (const float*)&bv[k];
                #pragma unroll
                for (int r = 0; r < 4; ++r)
                    Ylds[base + r * 8] = f2bf(acc[k][nt][r] + bp[r]);
            }
        }
    }

    // ---- stage-2 B frags (A matrix) straight from global (L1-resident) ----
    bf16x8 bfrag2[2][3];
    #pragma unroll
    for (int nt2 = 0; nt2 < 2; ++nt2) {
        int w = nt2 * 16 + wl;
        #pragma unroll
        for (int kb2 = 0; kb2 < 3; ++kb2) {
            frag_u fr;
            #pragma unroll
            for (int p = 0; p < 4; ++p) {
                int v0 = q4 * 8 + 2 * p;
                float a0 = (w < 25 && v0     < 25) ? A[(kb2 * 25 + v0) * 25 + w]     : 0.f;
                float a1 = (w < 25 && v0 + 1 < 25) ? A[(kb2 * 25 + v0 + 1) * 25 + w] : 0.f;
                fr.u[p] = cvtpk(a0, a1);
            }
            bfrag2[nt2][kb2] = fr.v;
        }
    }

    // ---- stage 2: out_t(16x25 per wave) = Yt(16x96) @ A(96x25), per t ----
    float ssum[4] = {0.f, 0.f, 0.f, 0.f};
    float ssq[4]  = {0.f, 0.f, 0.f, 0.f};
    short* wstile = ws + (size_t)bid * TSZ;
    const int cl0 = q4 * 4;                  // c_local base
    const int c0  = wave * 16 + cl0;         // global channel base

    #pragma unroll
    for (int t = 0; t < TT; ++t) {
        bf16x8 a2[3];
        #pragma unroll
        for (int kb2 = 0; kb2 < 3; ++kb2)
            a2[kb2] = *(const bf16x8*)&Ylds[wbase + (t * 3 + kb2) * 512 + lane * 8];

        f32x4 acc2[2];
        #pragma unroll
        for (int nt2 = 0; nt2 < 2; ++nt2) {
            f32x4 zf = {0.f, 0.f, 0.f, 0.f};
            acc2[nt2] = zf;
            #pragma unroll
            for (int kb2 = 0; kb2 < 3; ++kb2)
                acc2[nt2] = __builtin_amdgcn_mfma_f32_16x16x32_bf16(
                    a2[kb2], bfrag2[nt2][kb2], acc2[nt2], 0, 0, 0);
        }

        #pragma unroll
        for (int nt2 = 0; nt2 < 2; ++nt2) {
            int w = nt2 * 16 + wl;
            bool valid = (w < 25);
            #pragma unroll
            for (int r = 0; r < 4; ++r) {
                float val = acc2[nt2][r];
                if (valid) {
                    wstile[(c0 + r) * 75 + t * 25 + w] = f2h(val);
                    ssum[r] += val;
                    ssq[r]  += val * val;
                }
            }
        }
    }

    // ---- per-channel partial stats: reduce over the 16 w-lanes ----
    #pragma unroll
    for (int r = 0; r < 4; ++r) {
        float s = ssum[r], q = ssq[r];
        #pragma unroll
        for (int d = 1; d < 16; d <<= 1) {
            s += __shfl_xor(s, d);
            q += __shfl_xor(q, d);
        }
        if (wl == 0) {
            int c = c0 + r;
            int slot = bid & 63;
            atomicAdd(&stats_part[slot * 128 + c], s);
            atomicAdd(&stats_part[slot * 128 + 64 + c], q);
        }
    }
}

__global__ void sgc_finalize(const float* __restrict__ stats_part,
                             const float* __restrict__ gamma,
                             const float* __restrict__ beta,
                             float* __restrict__ scaleshift)
{
    int c = threadIdx.x;  // 64 threads
    float s = 0.f, q = 0.f;
    #pragma unroll 8
    for (int slot = 0; slot < 64; ++slot) {
        s += stats_part[slot * 128 + c];
        q += stats_part[slot * 128 + 64 + c];
    }
    const float invN = 1.f / 480000.f;
    float mean = s * invN;
    float var  = q * invN - mean * mean;
    float rstd = rsqrtf(var + 1e-5f);
    float sc = rstd * gamma[c];
    scaleshift[c]      = sc;
    scaleshift[64 + c] = beta[c] - mean * sc;
}

// ---- norm: dense fp16 tile (linear read) -> fp32 out (segmented linear) ----
__global__ __launch_bounds__(256) void sgc_normws(
    const short* __restrict__ ws, const float* __restrict__ scaleshift,
    float* __restrict__ out)
{
    const int bid   = blockIdx.x;          // 6400
    const int b     = bid / 100;
    const int chunk = bid % 100;
    const short* tile = ws + (size_t)bid * TSZ;
    float* ob = out + (size_t)b * 480000 + (size_t)chunk * NPIX;

    #pragma unroll
    for (int j = 0; j < 19; ++j) {
        int i = threadIdx.x + 256 * j;
        if (i < 4800) {
            int c = i / 75;
            int r = i - c * 75;
            float y = h2f(tile[i]);
            ob[c * 7500 + r] = y * scaleshift[c] + scaleshift[64 + c];
        }
    }
}

// ===========================================================================
// Fallback path (workspace too small): v2 kernels — scattered fp32 out +
// in-place norm.
// ===========================================================================
__global__ __launch_bounds__(256, 3) void sgc_main_fb(
    const float* __restrict__ x, const float* __restrict__ W,
    const float* __restrict__ bias, const float* __restrict__ A,
    float* __restrict__ out, float* __restrict__ stats_part)
{
    __shared__ __align__(16) short Ylds[18432];
    __shared__ __align__(16) short Acat[3072];

    const int tid  = threadIdx.x;
    const int lane = tid & 63;
    const int wave = tid >> 6;
    const int q4   = lane >> 4;
    const int wl   = lane & 15;
    const int bid  = blockIdx.x;
    const int b    = bid / 100;
    const int t0   = (bid % 100) * TT;

    {
        bf16x8 z8 = {0,0,0,0,0,0,0,0};
        #pragma unroll
        for (int j = 0; j < 3; ++j) {
            int s = tid + 256 * j;
            if (s < 576)
                *(bf16x8*)&Ylds[(s >> 4) * 512 + 384 + (s & 15) * 8] = z8;
        }
    }

    #pragma unroll
    for (int j = 0; j < 2; ++j) {
        int g = tid + 256 * j;
        if (g < 384) {
            int tile = g >> 6;
            int kb2  = tile >> 1, nt2 = tile & 1;
            int oct  = (g >> 4) & 3;
            int w    = nt2 * 16 + (g & 15);
            frag_u fr;
            #pragma unroll
            for (int p = 0; p < 4; ++p) {
                int v0 = oct * 8 + 2 * p;
                float a0 = (w < 25 && v0     < 25) ? A[(kb2 * 25 + v0) * 25 + w]     : 0.f;
                float a1 = (w < 25 && v0 + 1 < 25) ? A[(kb2 * 25 + v0 + 1) * 25 + w] : 0.f;
                fr.u[p] = cvtpk(a0, a1);
            }
            *(bf16x8*)&Acat[g * 8] = fr.v;
        }
    }

    bf16x8 wfrag[3][2];
    #pragma unroll
    for (int mti = 0; mti < 3; ++mti) {
        int o = (wave * 3 + mti) * 16 + wl;
        #pragma unroll
        for (int kb = 0; kb < 2; ++kb) {
            int ci0 = kb * 32 + q4 * 8;
            const float4 f0 = *(const float4*)&W[o * 64 + ci0];
            const float4 f1 = *(const float4*)&W[o * 64 + ci0 + 4];
            frag_u fr;
            fr.u[0] = cvtpk(f0.x, f0.y);
            fr.u[1] = cvtpk(f0.z, f0.w);
            fr.u[2] = cvtpk(f1.x, f1.y);
            fr.u[3] = cvtpk(f1.z, f1.w);
            wfrag[mti][kb] = fr.v;
        }
    }

    const float* xp = x + (size_t)b * 480000 + (size_t)t0 * 25;
    f32x4 acc[3][NT1];
    #pragma unroll
    for (int mti = 0; mti < 3; ++mti)
        #pragma unroll
        for (int nt = 0; nt < NT1; ++nt) {
            f32x4 zf = {0.f, 0.f, 0.f, 0.f};
            acc[mti][nt] = zf;
        }

    #pragma unroll
    for (int nt = 0; nt < NT1; ++nt) {
        int n = nt * 16 + wl;
        if (n > NPIX - 1) n = NPIX - 1;
        int loff = q4 * 60000 + n;
        bf16x8 xb[2];
        #pragma unroll
        for (int kb = 0; kb < 2; ++kb) {
            float xv[8];
            #pragma unroll
            for (int jj = 0; jj < 8; ++jj)
                xv[jj] = (xp + (kb * 32 + jj) * 7500)[loff];
            frag_u fr;
            #pragma unroll
            for (int p = 0; p < 4; ++p)
                fr.u[p] = cvtpk(xv[2 * p], xv[2 * p + 1]);
            xb[kb] = fr.v;
        }
        #pragma unroll
        for (int mti = 0; mti < 3; ++mti) {
            acc[mti][nt] = __builtin_amdgcn_mfma_f32_16x16x32_bf16(
                wfrag[mti][0], xb[0], acc[mti][nt], 0, 0, 0);
            acc[mti][nt] = __builtin_amdgcn_mfma_f32_16x16x32_bf16(
                wfrag[mti][1], xb[1], acc[mti][nt], 0, 0, 0);
        }
    }

    float4 bv[3];
    #pragma unroll
    for (int mti = 0; mti < 3; ++mti)
        bv[mti] = *(const float4*)&bias[(wave * 3 + mti) * 16 + q4 * 4];

    __syncthreads();

    #pragma unroll
    for (int nt = 0; nt < NT1; ++nt) {
        int n = nt * 16 + wl;
        if (n < NPIX) {
            int t = n / 25, v = n % 25;
            #pragma unroll
            for (int mti = 0; mti < 3; ++mti) {
                int wt = wave * 3 + mti;
                int k  = wt >> 2, cq = wt & 3;
                int kv = k * 32 + v;
                int sbase = ((t * 4 + cq) * 3 + k) * 512
                          + ((kv >> 3) & 3) * 128 + q4 * 32 + (kv & 7);
                const float* bp = (const float*)&bv[mti];
                #pragma unroll
                for (int r = 0; r < 4; ++r)
                    Ylds[sbase + r * 8] = f2bf(acc[mti][nt][r] + bp[r]);
            }
        }
    }
    __syncthreads();

    bf16x8 bfrag2[2][3];
    #pragma unroll
    for (int nt2 = 0; nt2 < 2; ++nt2)
        #pragma unroll
        for (int kb2 = 0; kb2 < 3; ++kb2)
            bfrag2[nt2][kb2] = *(const bf16x8*)&Acat[((kb2 * 2 + nt2) * 64 + lane) * 8];

    float ssum[4] = {0.f, 0.f, 0.f, 0.f};
    float ssq[4]  = {0.f, 0.f, 0.f, 0.f};
    const int c0 = wave * 16 + q4 * 4;

    #pragma unroll
    for (int t = 0; t < TT; ++t) {
        bf16x8 a2[3];
        #pragma unroll
        for (int kb2 = 0; kb2 < 3; ++kb2)
            a2[kb2] = *(const bf16x8*)&Ylds[(((t * 4 + wave) * 3 + kb2) * 64 + lane) * 8];

        f32x4 acc2[2];
        #pragma unroll
        for (int nt2 = 0; nt2 < 2; ++nt2) {
            f32x4 zf = {0.f, 0.f, 0.f, 0.f};
            acc2[nt2] = zf;
            #pragma unroll
            for (int kb2 = 0; kb2 < 3; ++kb2)
                acc2[nt2] = __builtin_amdgcn_mfma_f32_16x16x32_bf16(
                    a2[kb2], bfrag2[nt2][kb2], acc2[nt2], 0, 0, 0);
        }

        #pragma unroll
        for (int nt2 = 0; nt2 < 2; ++nt2) {
            int w = nt2 * 16 + wl;
            bool valid = (w < 25);
            #pragma unroll
            for (int r = 0; r < 4; ++r) {
                float val = acc2[nt2][r];
                if (valid) {
                    out[(size_t)((b * 64 + c0 + r) * 300 + t0 + t) * 25 + w] = val;
                    ssum[r] += val;
                    ssq[r]  += val * val;
                }
            }
        }
    }

    #pragma unroll
    for (int r = 0; r < 4; ++r) {
        float s = ssum[r], q = ssq[r];
        #pragma unroll
        for (int d = 1; d < 16; d <<= 1) {
            s += __shfl_xor(s, d);
            q += __shfl_xor(q, d);
        }
        if (wl == 0) {
            int c = c0 + r;
            int slot = bid & 63;
            atomicAdd(&stats_part[slot * 128 + c], s);
            atomicAdd(&stats_part[slot * 128 + 64 + c], q);
        }
    }
}

__global__ __launch_bounds__(256) void sgc_norm_fb(float* __restrict__ out,
                                                   const float* __restrict__ scaleshift)
{
    const int total4 = 30720000 / 4;
    int stride = gridDim.x * 256;
    for (int i = blockIdx.x * 256 + threadIdx.x; i < total4; i += stride) {
        int c = (i / 1875) & 63;
        float sc = scaleshift[c], sh = scaleshift[64 + c];
        float4 v = *((float4*)out + i);
        v.x = v.x * sc + sh;
        v.y = v.y * sc + sh;
        v.z = v.z * sc + sh;
        v.w = v.w * sc + sh;
        *((float4*)out + i) = v;
    }
}

extern "C" void kernel_launch(void* const* d_in, const int* in_sizes, int n_in,
                              void* d_out, int out_size, void* d_ws, size_t ws_size,
                              hipStream_t stream)
{
    const float* x     = (const float*)d_in[0];
    const float* W     = (const float*)d_in[1];
    const float* bias  = (const float*)d_in[2];
    const float* A     = (const float*)d_in[3];
    const float* gamma = (const float*)d_in[4];
    const float* beta  = (const float*)d_in[5];
    float* out = (float*)d_out;

    const size_t tile_bytes = (size_t)NBLK * TSZ * sizeof(short);   // 61.44 MB
    const size_t need = tile_bytes + 64 * 128 * sizeof(float) + 128 * sizeof(float);

    if (ws_size >= need) {
        short* tiles      = (short*)d_ws;
        float* stats      = (float*)((char*)d_ws + tile_bytes);
        float* scaleshift = stats + 64 * 128;

        hipMemsetAsync(stats, 0, 64 * 128 * sizeof(float), stream);
        sgc_main<<<NBLK, 256, 0, stream>>>(x, W, bias, A, tiles, stats);
        sgc_finalize<<<1, 64, 0, stream>>>(stats, gamma, beta, scaleshift);
        sgc_normws<<<NBLK, 256, 0, stream>>>(tiles, scaleshift, out);
    } else {
        float* stats      = (float*)d_ws;
        float* scaleshift = stats + 64 * 128;

        hipMemsetAsync(stats, 0, 64 * 128 * sizeof(float), stream);
        sgc_main_fb<<<NBLK, 256, 0, stream>>>(x, W, bias, A, out, stats);
        sgc_finalize<<<1, 64, 0, stream>>>(stats, gamma, beta, scaleshift);
        sgc_norm_fb<<<4096, 256, 0, stream>>>(out, scaleshift);
    }
}